// Round 10
// baseline (469.713 us; speedup 1.0000x reference)
//
#include <hip/hip_runtime.h>
#include <hip/hip_fp16.h>

typedef __bf16 bf16;
typedef bf16 bf16x8 __attribute__((ext_vector_type(8)));
typedef float f32x4 __attribute__((ext_vector_type(4)));

#define LD64  80   // padded LDS row stride (elems) for 64-wide tiles
#define LD128 144  // padded LDS row stride for 128-wide tiles

static __device__ __forceinline__ f32x4 mfma16(bf16x8 a, bf16x8 b, f32x4 c) {
    return __builtin_amdgcn_mfma_f32_16x16x32_bf16(a, b, c, 0, 0, 0);
}

static __device__ __forceinline__ bf16x8 cvt8(float4 a, float4 b) {
    bf16x8 v;
    v[0] = (bf16)a.x; v[1] = (bf16)a.y; v[2] = (bf16)a.z; v[3] = (bf16)a.w;
    v[4] = (bf16)b.x; v[5] = (bf16)b.y; v[6] = (bf16)b.z; v[7] = (bf16)b.w;
    return v;
}

static __device__ __forceinline__ uint32_t pack_bf16(float lo, float hi) {
    bf16 a = (bf16)lo, b = (bf16)hi;
    uint16_t ua = *(uint16_t*)&a, ub = *(uint16_t*)&b;
    return ((uint32_t)ub << 16) | (uint32_t)ua;
}

// --- helpers for the fallback (f16 agg) path ---
static __device__ __forceinline__ uint32_t pack_f16(float lo, float hi) {
    __half hl = __float2half_rn(lo), hh = __float2half_rn(hi);
    uint16_t a = *(uint16_t*)&hl, b = *(uint16_t*)&hh;
    return ((uint32_t)b << 16) | (uint32_t)a;
}
static __device__ __forceinline__ void atomic_pk_f16(__half* addr, uint32_t v) {
    asm volatile("global_atomic_pk_add_f16 %0, %1, off" :: "v"(addr), "v"(v) : "memory");
}
static __device__ __forceinline__ float h2f_lo(uint32_t u) {
    uint16_t s = (uint16_t)u; __half h = *(__half*)&s; return __half2float(h);
}
static __device__ __forceinline__ float h2f_hi(uint32_t u) {
    uint16_t s = (uint16_t)(u >> 16); __half h = *(__half*)&s; return __half2float(h);
}

// ===========================================================================
// hist_rk: cnt1 histogram for rel1; per-slot histograms cntA (i0-dest) /
// cntB (i1-dest) for rel2 with RANK capture -> atomic-free slot-partitioned
// scatter later.
// ===========================================================================
__global__ __launch_bounds__(256) void hist_rk_kernel(
    const int* __restrict__ r1, const int* __restrict__ r2,
    unsigned* __restrict__ cnt1, unsigned* __restrict__ cntA,
    unsigned* __restrict__ cntB, ushort2* __restrict__ rk2, int M1, int M2)
{
    int i = blockIdx.x * 256 + threadIdx.x;
    const int T = gridDim.x * 256;
    const int tot = M1 + M2;
    for (; i < tot; i += T) {
        if (i < M1) {
            atomicAdd(&cnt1[r1[i]], 1u);
        } else {
            const int e = i - M1;
            const int2 pr = *(const int2*)(r2 + 2 * e);
            unsigned ra = atomicAdd(&cntA[pr.x], 1u);
            unsigned rb = atomicAdd(&cntB[pr.y], 1u);
            rk2[e] = make_ushort2((unsigned short)ra, (unsigned short)rb);
        }
    }
}

// ===========================================================================
// Scan chain: rowp = exclusive prefix of per-node totals (cntA+cntB)
// ===========================================================================
__global__ __launch_bounds__(256) void scan_sums(
    const unsigned* __restrict__ cntA, const unsigned* __restrict__ cntB,
    unsigned* __restrict__ csum)
{
    __shared__ unsigned s[256];
    const int b = blockIdx.x, t = threadIdx.x;
    const int x = b * 512 + t, y = x + 256;
    s[t] = cntA[x] + cntB[x] + cntA[y] + cntB[y];
    __syncthreads();
    for (int d = 128; d > 0; d >>= 1) {
        if (t < d) s[t] += s[t + d];
        __syncthreads();
    }
    if (t == 0) csum[b] = s[0];
}

__global__ __launch_bounds__(256) void scan_chunkoff(unsigned* __restrict__ csum, int nch) {
    __shared__ unsigned s[2][256];
    const int t = threadIdx.x;
    if (nch > 256) {
        if (t == 0) {
            unsigned run = 0;
            for (int j = 0; j < nch; ++j) { unsigned v = csum[j]; csum[j] = run; run += v; }
        }
        return;
    }
    unsigned v = (t < nch) ? csum[t] : 0u;
    s[0][t] = v;
    __syncthreads();
    int src = 0;
    for (int d = 1; d < 256; d <<= 1) {
        int dst = src ^ 1;
        s[dst][t] = s[src][t] + (t >= d ? s[src][t - d] : 0u);
        __syncthreads();
        src = dst;
    }
    if (t < nch) csum[t] = s[src][t] - v;   // exclusive
}

__global__ __launch_bounds__(256) void scan_apply(
    const unsigned* __restrict__ cntA, const unsigned* __restrict__ cntB,
    const unsigned* __restrict__ csum, unsigned* __restrict__ rowp)
{
    __shared__ unsigned s[2][512];
    const int b = blockIdx.x, t = threadIdx.x;
    const unsigned base = csum[b];
    s[0][t] = cntA[b * 512 + t] + cntB[b * 512 + t];
    s[0][t + 256] = cntA[b * 512 + t + 256] + cntB[b * 512 + t + 256];
    __syncthreads();
    int src = 0;
    for (int d = 1; d < 512; d <<= 1) {
        int dst = src ^ 1;
        for (int i = t; i < 512; i += 256)
            s[dst][i] = s[src][i] + (i >= d ? s[src][i - d] : 0u);
        __syncthreads();
        src = dst;
    }
    for (int i = t; i < 512; i += 256) {
        const unsigned tot = cntA[b * 512 + i] + cntB[b * 512 + i];
        rowp[b * 512 + i] = base + s[src][i] - tot;
    }
}

// ===========================================================================
// MIX: blocks [0,SB) = atomic-free slot-partitioned scatter:
//   slot0 entry of edge e -> sps[rowp[i0] + rkA] = i1
//   slot1 entry           -> sps[rowp[i1] + cntA[i1] + rkB] = i0
// blocks [SB,...) = prep3 (P0/P1 + unscaled rel1 MLP -> aggu).
// ===========================================================================
__global__ __launch_bounds__(256) void mix_kernel(
    // scatter args
    const int* __restrict__ r2, const ushort2* __restrict__ rk2,
    const unsigned* __restrict__ rowp, const unsigned* __restrict__ cntA,
    int* __restrict__ sps, int M2, int SB,
    // prep args
    const float* __restrict__ emb,
    const float* __restrict__ mW1, const float* __restrict__ mb1,   // 128x128,128
    const float* __restrict__ r1W1, const float* __restrict__ r1b1, // 64x64,64
    const float* __restrict__ r1W2, const float* __restrict__ r1b2,
    bf16* __restrict__ P0, bf16* __restrict__ P1,
    float* __restrict__ aggu, int N, int PT)
{
    __shared__ bf16 sG[64 * LD64];
    __shared__ bf16 sH[64 * LD64];
    __shared__ bf16 sW1t[64 * LD64];
    __shared__ bf16 sW2t[64 * LD64];
    __shared__ float sB1[64], sB2[64];

    const int t = threadIdx.x;

    if ((int)blockIdx.x < SB) {   // ---- atomic-free scatter (per edge) ----
        const int T = SB * 256;
        for (int e = blockIdx.x * 256 + t; e < M2; e += T) {
            const int2 pr = *(const int2*)(r2 + 2 * e);
            const ushort2 rr = rk2[e];
            sps[rowp[pr.x] + (unsigned)rr.x] = pr.y;
            sps[rowp[pr.y] + cntA[pr.y] + (unsigned)rr.y] = pr.x;
        }
        return;
    }

    // ---- prep3 + rel1 ----
    const int bid = blockIdx.x - SB;
    const int G = gridDim.x - SB;
    const int wave = t >> 6, lane = t & 63;
    const int l15 = lane & 15, quad = lane >> 4;
    const int r = t >> 2, p = t & 3;

    for (int i = t; i < 64 * 64; i += 256) {
        int k = i >> 6, n = i & 63;
        sW1t[n * LD64 + k] = (bf16)r1W1[i];
        sW2t[n * LD64 + k] = (bf16)r1W2[i];
    }
    if (t < 64) { sB1[t] = r1b1[t]; sB2[t] = r1b2[t]; }

    bf16x8 wf0[2][2], wf1[2][2];
    float biasv[2];
    #pragma unroll
    for (int j = 0; j < 2; ++j) {
        const int n = (wave * 2 + j) * 16 + l15;
        biasv[j] = mb1[n];
        #pragma unroll
        for (int kt = 0; kt < 2; ++kt) {
            bf16x8 f0, f1;
            #pragma unroll
            for (int e = 0; e < 8; ++e) {
                int k = kt * 32 + quad * 8 + e;
                f0[e] = (bf16)mW1[k * 128 + n];
                f1[e] = (bf16)mW1[(64 + k) * 128 + n];
            }
            wf0[j][kt] = f0;
            wf1[j][kt] = f1;
        }
    }

    for (int tile = bid; tile < PT; tile += G) {
        __syncthreads();
        const int base = tile * 64;
        const int R = base + r;
        if (R < N) {
            const float4* src = (const float4*)(emb + (size_t)R * 64 + p * 16);
            float4 v0 = src[0], v1 = src[1], v2 = src[2], v3 = src[3];
            *(bf16x8*)&sG[r * LD64 + p * 16 + 0] = cvt8(v0, v1);
            *(bf16x8*)&sG[r * LD64 + p * 16 + 8] = cvt8(v2, v3);
        }
        __syncthreads();

        // --- P-part ---
        f32x4 a0[4][2], a1[4][2];
        #pragma unroll
        for (int mt = 0; mt < 4; ++mt)
            #pragma unroll
            for (int j = 0; j < 2; ++j) {
                a0[mt][j] = (f32x4){0.f, 0.f, 0.f, 0.f};
                a1[mt][j] = (f32x4){0.f, 0.f, 0.f, 0.f};
            }
        #pragma unroll
        for (int mt = 0; mt < 4; ++mt)
            #pragma unroll
            for (int kt = 0; kt < 2; ++kt) {
                bf16x8 a = *(const bf16x8*)&sG[(mt * 16 + l15) * LD64 + kt * 32 + quad * 8];
                #pragma unroll
                for (int j = 0; j < 2; ++j) {
                    a0[mt][j] = mfma16(a, wf0[j][kt], a0[mt][j]);
                    a1[mt][j] = mfma16(a, wf1[j][kt], a1[mt][j]);
                }
            }
        #pragma unroll
        for (int mt = 0; mt < 4; ++mt)
            #pragma unroll
            for (int j = 0; j < 2; ++j) {
                const int colb = (wave * 2 + j) * 16 + (l15 & ~1);
                const int odd = l15 & 1;
                #pragma unroll
                for (int rr = 0; rr < 4; ++rr) {
                    float v = a0[mt][j][rr] + biasv[j];
                    float o = __shfl_xor(v, 1);
                    float w = a1[mt][j][rr];
                    float ow = __shfl_xor(w, 1);
                    if ((rr >> 1) == odd) {
                        int node = base + mt * 16 + quad * 4 + rr;
                        if (node < N) {
                            *(uint32_t*)&P0[(size_t)node * 128 + colb] =
                                odd ? pack_bf16(o, v) : pack_bf16(v, o);
                            *(uint32_t*)&P1[(size_t)node * 128 + colb] =
                                odd ? pack_bf16(ow, w) : pack_bf16(w, ow);
                        }
                    }
                }
            }

        // --- rel1 MLP (unscaled) ---
        f32x4 acc[4];
        #pragma unroll
        for (int nt = 0; nt < 4; ++nt) acc[nt] = (f32x4){0.f, 0.f, 0.f, 0.f};
        #pragma unroll
        for (int kt = 0; kt < 2; ++kt) {
            bf16x8 a = *(const bf16x8*)&sG[(wave * 16 + l15) * LD64 + kt * 32 + quad * 8];
            #pragma unroll
            for (int nt = 0; nt < 4; ++nt) {
                bf16x8 bfr = *(const bf16x8*)&sW1t[(nt * 16 + l15) * LD64 + kt * 32 + quad * 8];
                acc[nt] = mfma16(a, bfr, acc[nt]);
            }
        }
        #pragma unroll
        for (int nt = 0; nt < 4; ++nt) {
            float bias = sB1[nt * 16 + l15];
            #pragma unroll
            for (int rr = 0; rr < 4; ++rr) {
                float v = acc[nt][rr] + bias;
                v = v > 0.f ? v : 0.f;
                sH[(wave * 16 + quad * 4 + rr) * LD64 + nt * 16 + l15] = (bf16)v;
            }
        }
        __syncthreads();

        f32x4 acc2[4];
        #pragma unroll
        for (int nt = 0; nt < 4; ++nt) acc2[nt] = (f32x4){0.f, 0.f, 0.f, 0.f};
        #pragma unroll
        for (int kt = 0; kt < 2; ++kt) {
            bf16x8 a = *(const bf16x8*)&sH[(wave * 16 + l15) * LD64 + kt * 32 + quad * 8];
            #pragma unroll
            for (int nt = 0; nt < 4; ++nt) {
                bf16x8 bfr = *(const bf16x8*)&sW2t[(nt * 16 + l15) * LD64 + kt * 32 + quad * 8];
                acc2[nt] = mfma16(a, bfr, acc2[nt]);
            }
        }
        #pragma unroll
        for (int nt = 0; nt < 4; ++nt) {
            float bias = sB2[nt * 16 + l15];
            #pragma unroll
            for (int rr = 0; rr < 4; ++rr) {
                int row = wave * 16 + quad * 4 + rr;
                int R2 = base + row;
                if (R2 < N)
                    aggu[(size_t)R2 * 64 + nt * 16 + l15] = acc2[nt][rr] + bias;
            }
        }
    }
}

// ===========================================================================
// seg_walk: accumulate sum of relu(cached + P[id]) over sps[s,e), 8-deep
// batched single loads. cached (clo,chi) is the node's own P-row value.
// ===========================================================================
static __device__ __forceinline__ void seg_walk(
    const int* __restrict__ sps, unsigned s, const unsigned e,
    const bf16* __restrict__ P, const int lane,
    const float clo, const float chi, float& alo, float& ahi)
{
    while (s < e) {
        const int cnt = (int)min(64u, e - s);
        int pid = 0;
        if (lane < cnt) pid = sps[s + lane];
        int j = 0;
        for (; j + 8 <= cnt; j += 8) {          // 8 loads in flight
            uint32_t dv[8];
            #pragma unroll
            for (int q = 0; q < 8; ++q) {
                const int id = __shfl(pid, j + q);
                dv[q] = *(const uint32_t*)(P + (size_t)id * 128 + lane * 2);
            }
            #pragma unroll
            for (int q = 0; q < 8; ++q) {
                float lo = __uint_as_float(dv[q] << 16) + clo;
                float hi = __uint_as_float(dv[q] & 0xffff0000u) + chi;
                alo += fmaxf(lo, 0.f);
                ahi += fmaxf(hi, 0.f);
            }
        }
        for (; j + 4 <= cnt; j += 4) {
            uint32_t dv[4];
            #pragma unroll
            for (int q = 0; q < 4; ++q) {
                const int id = __shfl(pid, j + q);
                dv[q] = *(const uint32_t*)(P + (size_t)id * 128 + lane * 2);
            }
            #pragma unroll
            for (int q = 0; q < 4; ++q) {
                float lo = __uint_as_float(dv[q] << 16) + clo;
                float hi = __uint_as_float(dv[q] & 0xffff0000u) + chi;
                alo += fmaxf(lo, 0.f);
                ahi += fmaxf(hi, 0.f);
            }
        }
        for (; j < cnt; ++j) {
            const int id = __shfl(pid, j);
            const uint32_t d = *(const uint32_t*)(P + (size_t)id * 128 + lane * 2);
            float lo = __uint_as_float(d << 16) + clo;
            float hi = __uint_as_float(d & 0xffff0000u) + chi;
            alo += fmaxf(lo, 0.f);
            ahi += fmaxf(hi, 0.f);
        }
        s += cnt;
    }
}

// ===========================================================================
// rel2 fused aggregation, slot-partitioned walk: the node's own P-row is
// cached in registers; each entry costs ONE row load. Then per 32-node
// group one MFMA sweep: agg = cnt1*aggu + H0@W2[:, :64]+H1@W2[:, 64:] + c*b2.
// ===========================================================================
__global__ __launch_bounds__(256) void rel2_fused_kernel(
    const bf16* __restrict__ P0, const bf16* __restrict__ P1,
    const int* __restrict__ sps,
    const unsigned* __restrict__ rowp, const unsigned* __restrict__ cntA,
    const unsigned* __restrict__ cnt1,
    const float* __restrict__ W2, const float* __restrict__ b2,   // 128x128,128
    float* agg, int N, int numGroups)
{
    const int HLD = 136;
    __shared__ bf16 hT[2][32 * 136];
    __shared__ float sCf[2][32];

    const int t = threadIdx.x;
    const int wave = t >> 6, lane = t & 63;
    const int l15 = lane & 15, quad = lane >> 4;

    bf16x8 w2f[2][4];
    #pragma unroll
    for (int s = 0; s < 2; ++s)
        #pragma unroll
        for (int kt = 0; kt < 4; ++kt) {
            bf16x8 f;
            #pragma unroll
            for (int e = 0; e < 8; ++e) {
                int k = kt * 32 + quad * 8 + e;
                f[e] = (bf16)W2[k * 128 + s * 64 + wave * 16 + l15];
            }
            w2f[s][kt] = f;
        }
    const int col = wave * 16 + l15;
    const float b2a = b2[col], b2b = b2[64 + col];

    for (int g = blockIdx.x; g < numGroups; g += gridDim.x) {
        const int gb = g * 32;
        __syncthreads();   // protect hT/sCf against previous group's GEMM

        // ---- walk: wave fills rows [wave*8, wave*8+8) ----
        for (int k = 0; k < 8; ++k) {
            const int n = gb + wave * 8 + k;
            float h0lo = 0.f, h0hi = 0.f, h1lo = 0.f, h1hi = 0.f;
            float c0f = 0.f, c1f = 0.f;
            if (n < N) {
                const unsigned e0 = rowp[n], e1 = rowp[n + 1];
                const unsigned cA = cntA[n];
                c0f = (float)cA;
                c1f = (float)(e1 - e0 - cA);
                if (cA) {   // slot-0 entries: h = relu(P0[n] + P1[other])
                    const uint32_t pd = *(const uint32_t*)(P0 + (size_t)n * 128 + lane * 2);
                    const float clo = __uint_as_float(pd << 16);
                    const float chi = __uint_as_float(pd & 0xffff0000u);
                    seg_walk(sps, e0, e0 + cA, P1, lane, clo, chi, h0lo, h0hi);
                }
                if (e1 > e0 + cA) {   // slot-1: h = relu(P0[other] + P1[n])
                    const uint32_t pd = *(const uint32_t*)(P1 + (size_t)n * 128 + lane * 2);
                    const float clo = __uint_as_float(pd << 16);
                    const float chi = __uint_as_float(pd & 0xffff0000u);
                    seg_walk(sps, e0 + cA, e1, P0, lane, clo, chi, h1lo, h1hi);
                }
            }
            const int row = wave * 8 + k;
            *(uint32_t*)&hT[0][row * HLD + lane * 2] = pack_bf16(h0lo, h0hi);
            *(uint32_t*)&hT[1][row * HLD + lane * 2] = pack_bf16(h1lo, h1hi);
            if (lane == 0) { sCf[0][row] = c0f; sCf[1][row] = c1f; }
        }
        __syncthreads();

        // ---- GEMM: out[32 nodes][wave's 16 cols] = sum_s H_s @ W2half[s] ----
        f32x4 acc[2];
        #pragma unroll
        for (int mt = 0; mt < 2; ++mt) acc[mt] = (f32x4){0.f, 0.f, 0.f, 0.f};
        #pragma unroll
        for (int s = 0; s < 2; ++s)
            #pragma unroll
            for (int mt = 0; mt < 2; ++mt)
                #pragma unroll
                for (int kt = 0; kt < 4; ++kt) {
                    bf16x8 a = *(const bf16x8*)&hT[s][(mt * 16 + l15) * HLD + kt * 32 + quad * 8];
                    acc[mt] = mfma16(a, w2f[s][kt], acc[mt]);
                }
        #pragma unroll
        for (int mt = 0; mt < 2; ++mt)
            #pragma unroll
            for (int rr = 0; rr < 4; ++rr) {
                const int row = mt * 16 + quad * 4 + rr;
                const int n = gb + row;
                if (n < N) {
                    float* ap = agg + (size_t)n * 64 + col;
                    const float au = *ap;                 // unscaled rel1 MLP out
                    *ap = (float)cnt1[n] * au + acc[mt][rr]
                        + sCf[0][row] * b2a + sCf[1][row] * b2b;
                }
            }
    }
}

// ===========================================================================
// update: out = relu([emb||agg] @ W1 + b1) @ W2 + b2 (agg aliases out)
// ===========================================================================
__global__ __launch_bounds__(256) void update_kernel(
    const float* __restrict__ emb, const float* agg,
    const float* __restrict__ W1, const float* __restrict__ b1,  // 128x64, 64
    const float* __restrict__ W2, const float* __restrict__ b2,  // 64x64, 64
    float* out, int N, int numTiles)
{
    __shared__ bf16 sW1t[64 * LD128];
    __shared__ bf16 sW2t[64 * LD64];
    __shared__ bf16 sU[64 * LD128];
    __shared__ bf16 sH[64 * LD64];
    __shared__ float sB1[64], sB2[64];

    const int t = threadIdx.x;
    const int wave = t >> 6, lane = t & 63;
    const int l15 = lane & 15, quad = lane >> 4;
    const int r = t >> 2, p = t & 3;

    for (int i = t; i < 128 * 64; i += 256) {
        int k = i >> 6, n = i & 63;
        sW1t[n * LD128 + k] = (bf16)W1[i];
    }
    for (int i = t; i < 64 * 64; i += 256) {
        int k = i >> 6, n = i & 63;
        sW2t[n * LD64 + k] = (bf16)W2[i];
    }
    if (t < 64) { sB1[t] = b1[t]; sB2[t] = b2[t]; }

    for (int tile = blockIdx.x; tile < numTiles; tile += gridDim.x) {
        __syncthreads();
        const int base = tile * 64;
        {
            const int R = base + r;
            if (R < N) {
                const float* srcp = (p < 2) ? (emb + (size_t)R * 64 + p * 32)
                                            : (agg + (size_t)R * 64 + (p - 2) * 32);
                const float4* src = (const float4*)srcp;
                #pragma unroll
                for (int i = 0; i < 4; ++i)
                    *(bf16x8*)&sU[r * LD128 + p * 32 + i * 8] = cvt8(src[2 * i], src[2 * i + 1]);
            }
        }
        __syncthreads();

        f32x4 acc[4];
        #pragma unroll
        for (int nt = 0; nt < 4; ++nt) acc[nt] = (f32x4){0.f, 0.f, 0.f, 0.f};
        #pragma unroll
        for (int kt = 0; kt < 4; ++kt) {
            bf16x8 a = *(const bf16x8*)&sU[(wave * 16 + l15) * LD128 + kt * 32 + quad * 8];
            #pragma unroll
            for (int nt = 0; nt < 4; ++nt) {
                bf16x8 bfr = *(const bf16x8*)&sW1t[(nt * 16 + l15) * LD128 + kt * 32 + quad * 8];
                acc[nt] = mfma16(a, bfr, acc[nt]);
            }
        }
        #pragma unroll
        for (int nt = 0; nt < 4; ++nt) {
            float bias = sB1[nt * 16 + l15];
            #pragma unroll
            for (int rr = 0; rr < 4; ++rr) {
                float v = acc[nt][rr] + bias;
                v = v > 0.f ? v : 0.f;
                sH[(wave * 16 + quad * 4 + rr) * LD64 + nt * 16 + l15] = (bf16)v;
            }
        }
        __syncthreads();

        f32x4 acc2[4];
        #pragma unroll
        for (int nt = 0; nt < 4; ++nt) acc2[nt] = (f32x4){0.f, 0.f, 0.f, 0.f};
        #pragma unroll
        for (int kt = 0; kt < 2; ++kt) {
            bf16x8 a = *(const bf16x8*)&sH[(wave * 16 + l15) * LD64 + kt * 32 + quad * 8];
            #pragma unroll
            for (int nt = 0; nt < 4; ++nt) {
                bf16x8 bfr = *(const bf16x8*)&sW2t[(nt * 16 + l15) * LD64 + kt * 32 + quad * 8];
                acc2[nt] = mfma16(a, bfr, acc2[nt]);
            }
        }
        #pragma unroll
        for (int nt = 0; nt < 4; ++nt) {
            float bias = sB2[nt * 16 + l15];
            #pragma unroll
            for (int rr = 0; rr < 4; ++rr) {
                int row = wave * 16 + quad * 4 + rr;
                int R = base + row;
                if (R < N)
                    out[(size_t)R * 64 + nt * 16 + l15] = acc2[nt][rr] + bias;
            }
        }
    }
}

// ===========================================================================
// Fallback path (workspace too small): f16 agg + pk atomics (proven).
// ===========================================================================
__global__ __launch_bounds__(256) void rel1_fb_kernel(
    const float* __restrict__ emb, const int* __restrict__ idx,
    const float* __restrict__ W1, const float* __restrict__ b1,
    const float* __restrict__ W2, const float* __restrict__ b2,
    __half* __restrict__ agg, int M, int numTiles)
{
    __shared__ bf16 sW1t[64 * LD64];
    __shared__ bf16 sW2t[64 * LD64];
    __shared__ bf16 sG[64 * LD64];
    __shared__ bf16 sH[64 * LD64];
    __shared__ float sB1[64], sB2[64];
    __shared__ int sIdx[64];

    const int t = threadIdx.x;
    const int wave = t >> 6, lane = t & 63;
    const int l15 = lane & 15, quad = lane >> 4;
    const int r = t >> 2, p = t & 3;

    for (int i = t; i < 64 * 64; i += 256) {
        int k = i >> 6, n = i & 63;
        sW1t[n * LD64 + k] = (bf16)W1[i];
        sW2t[n * LD64 + k] = (bf16)W2[i];
    }
    if (t < 64) { sB1[t] = b1[t]; sB2[t] = b2[t]; }

    for (int tile = blockIdx.x; tile < numTiles; tile += gridDim.x) {
        __syncthreads();
        const int base = tile * 64;
        int id = -1;
        { int R = base + r; if (R < M) id = idx[R]; }
        if (p == 0) sIdx[r] = id;
        if (id >= 0) {
            const float4* src = (const float4*)(emb + (size_t)id * 64 + p * 16);
            float4 v0 = src[0], v1 = src[1], v2 = src[2], v3 = src[3];
            *(bf16x8*)&sG[r * LD64 + p * 16 + 0] = cvt8(v0, v1);
            *(bf16x8*)&sG[r * LD64 + p * 16 + 8] = cvt8(v2, v3);
        }
        __syncthreads();

        f32x4 acc[4];
        #pragma unroll
        for (int nt = 0; nt < 4; ++nt) acc[nt] = (f32x4){0.f, 0.f, 0.f, 0.f};
        #pragma unroll
        for (int kt = 0; kt < 2; ++kt) {
            bf16x8 a = *(const bf16x8*)&sG[(wave * 16 + l15) * LD64 + kt * 32 + quad * 8];
            #pragma unroll
            for (int nt = 0; nt < 4; ++nt) {
                bf16x8 bfr = *(const bf16x8*)&sW1t[(nt * 16 + l15) * LD64 + kt * 32 + quad * 8];
                acc[nt] = mfma16(a, bfr, acc[nt]);
            }
        }
        #pragma unroll
        for (int nt = 0; nt < 4; ++nt) {
            float bias = sB1[nt * 16 + l15];
            #pragma unroll
            for (int rr = 0; rr < 4; ++rr) {
                float v = acc[nt][rr] + bias;
                v = v > 0.f ? v : 0.f;
                sH[(wave * 16 + quad * 4 + rr) * LD64 + nt * 16 + l15] = (bf16)v;
            }
        }
        __syncthreads();

        f32x4 acc2[4];
        #pragma unroll
        for (int nt = 0; nt < 4; ++nt) acc2[nt] = (f32x4){0.f, 0.f, 0.f, 0.f};
        #pragma unroll
        for (int kt = 0; kt < 2; ++kt) {
            bf16x8 a = *(const bf16x8*)&sH[(wave * 16 + l15) * LD64 + kt * 32 + quad * 8];
            #pragma unroll
            for (int nt = 0; nt < 4; ++nt) {
                bf16x8 bfr = *(const bf16x8*)&sW2t[(nt * 16 + l15) * LD64 + kt * 32 + quad * 8];
                acc2[nt] = mfma16(a, bfr, acc2[nt]);
            }
        }
        #pragma unroll
        for (int nt = 0; nt < 4; ++nt) {
            float bias = sB2[nt * 16 + l15];
            const int colb = nt * 16 + (l15 & ~1);
            const int odd = l15 & 1;
            #pragma unroll
            for (int rr = 0; rr < 4; ++rr) {
                float v = acc2[nt][rr] + bias;
                float o = __shfl_xor(v, 1);
                if ((rr >> 1) == odd) {
                    int row = wave * 16 + quad * 4 + rr;
                    int id2 = sIdx[row];
                    if (id2 >= 0)
                        atomic_pk_f16(agg + (size_t)id2 * 64 + colb,
                                      odd ? pack_f16(o, v) : pack_f16(v, o));
                }
            }
        }
    }
}

__global__ __launch_bounds__(256) void rel2_fb_kernel(
    const float* __restrict__ emb, const int* __restrict__ idx,
    const float* __restrict__ W1, const float* __restrict__ b1,
    const float* __restrict__ W2, const float* __restrict__ b2,
    __half* __restrict__ agg, int M, int numTiles)
{
    __shared__ bf16 sG[64 * LD128];
    __shared__ bf16 sH[64 * LD128];
    __shared__ int sIdx[128];

    const int t = threadIdx.x;
    const int wave = t >> 6, lane = t & 63;
    const int l15 = lane & 15, quad = lane >> 4;
    const int r = t >> 2, p = t & 3;

    bf16x8 w1f[2][4], w2f[2][4];
    float bias1[2], bias2[2];
    #pragma unroll
    for (int j = 0; j < 2; ++j) {
        const int n = (wave * 2 + j) * 16 + l15;
        bias1[j] = b1[n];
        bias2[j] = b2[n];
        #pragma unroll
        for (int kt = 0; kt < 4; ++kt) {
            bf16x8 f1, f2;
            #pragma unroll
            for (int e = 0; e < 8; ++e) {
                int k = kt * 32 + quad * 8 + e;
                f1[e] = (bf16)W1[k * 128 + n];
                f2[e] = (bf16)W2[k * 128 + n];
            }
            w1f[j][kt] = f1;
            w2f[j][kt] = f2;
        }
    }

    for (int tile = blockIdx.x; tile < numTiles; tile += gridDim.x) {
        __syncthreads();
        const int base = tile * 64;
        int i0 = -1, i1 = -1;
        { int R = base + r; if (R < M) { i0 = idx[R * 2]; i1 = idx[R * 2 + 1]; } }
        if (p == 0) { sIdx[r * 2] = i0; sIdx[r * 2 + 1] = i1; }
        {
            int myid = (p < 2) ? i0 : i1;
            if (myid >= 0) {
                const float4* src = (const float4*)(emb + (size_t)myid * 64 + (p & 1) * 32);
                #pragma unroll
                for (int i = 0; i < 4; ++i)
                    *(bf16x8*)&sG[r * LD128 + p * 32 + i * 8] = cvt8(src[2 * i], src[2 * i + 1]);
            }
        }
        __syncthreads();

        f32x4 acc[4][2];
        #pragma unroll
        for (int mt = 0; mt < 4; ++mt)
            #pragma unroll
            for (int j = 0; j < 2; ++j) acc[mt][j] = (f32x4){0.f, 0.f, 0.f, 0.f};
        #pragma unroll
        for (int mt = 0; mt < 4; ++mt) {
            #pragma unroll
            for (int kt = 0; kt < 4; ++kt) {
                bf16x8 a = *(const bf16x8*)&sG[(mt * 16 + l15) * LD128 + kt * 32 + quad * 8];
                #pragma unroll
                for (int j = 0; j < 2; ++j) acc[mt][j] = mfma16(a, w1f[j][kt], acc[mt][j]);
            }
        }
        #pragma unroll
        for (int mt = 0; mt < 4; ++mt)
            #pragma unroll
            for (int j = 0; j < 2; ++j) {
                #pragma unroll
                for (int rr = 0; rr < 4; ++rr) {
                    float v = acc[mt][j][rr] + bias1[j];
                    v = v > 0.f ? v : 0.f;
                    sH[(mt * 16 + quad * 4 + rr) * LD128 + (wave * 2 + j) * 16 + l15] = (bf16)v;
                }
            }
        __syncthreads();

        f32x4 acc2[4][2];
        #pragma unroll
        for (int mt = 0; mt < 4; ++mt)
            #pragma unroll
            for (int j = 0; j < 2; ++j) acc2[mt][j] = (f32x4){0.f, 0.f, 0.f, 0.f};
        #pragma unroll
        for (int mt = 0; mt < 4; ++mt) {
            #pragma unroll
            for (int kt = 0; kt < 4; ++kt) {
                bf16x8 a = *(const bf16x8*)&sH[(mt * 16 + l15) * LD128 + kt * 32 + quad * 8];
                #pragma unroll
                for (int j = 0; j < 2; ++j) acc2[mt][j] = mfma16(a, w2f[j][kt], acc2[mt][j]);
            }
        }
        #pragma unroll
        for (int mt = 0; mt < 4; ++mt) {
            #pragma unroll
            for (int j = 0; j < 2; ++j) {
                const int colb = (wave * 2 + j) * 16 + (l15 & ~1);
                const int sel = colb >> 6;
                const int c = colb & 63;
                const int odd = l15 & 1;
                #pragma unroll
                for (int rr = 0; rr < 4; ++rr) {
                    float v = acc2[mt][j][rr] + bias2[j];
                    float o = __shfl_xor(v, 1);
                    if ((rr >> 1) == odd) {
                        int row = mt * 16 + quad * 4 + rr;
                        int id2 = sIdx[row * 2 + sel];
                        if (id2 >= 0)
                            atomic_pk_f16(agg + (size_t)id2 * 64 + c,
                                          odd ? pack_f16(o, v) : pack_f16(v, o));
                    }
                }
            }
        }
    }
}

__global__ __launch_bounds__(256) void update_fb_kernel(
    const float* __restrict__ emb, const __half* __restrict__ agg,
    const float* __restrict__ W1, const float* __restrict__ b1,
    const float* __restrict__ W2, const float* __restrict__ b2,
    float* __restrict__ out, int N, int numTiles)
{
    __shared__ bf16 sW1t[64 * LD128];
    __shared__ bf16 sW2t[64 * LD64];
    __shared__ bf16 sU[64 * LD128];
    __shared__ bf16 sH[64 * LD64];
    __shared__ float sB1[64], sB2[64];

    const int t = threadIdx.x;
    const int wave = t >> 6, lane = t & 63;
    const int l15 = lane & 15, quad = lane >> 4;
    const int r = t >> 2, p = t & 3;

    for (int i = t; i < 128 * 64; i += 256) {
        int k = i >> 6, n = i & 63;
        sW1t[n * LD128 + k] = (bf16)W1[i];
    }
    for (int i = t; i < 64 * 64; i += 256) {
        int k = i >> 6, n = i & 63;
        sW2t[n * LD64 + k] = (bf16)W2[i];
    }
    if (t < 64) { sB1[t] = b1[t]; sB2[t] = b2[t]; }

    for (int tile = blockIdx.x; tile < numTiles; tile += gridDim.x) {
        __syncthreads();
        const int base = tile * 64;
        {
            const int R = base + r;
            if (R < N) {
                if (p < 2) {
                    const float4* src = (const float4*)(emb + (size_t)R * 64 + p * 32);
                    #pragma unroll
                    for (int i = 0; i < 4; ++i)
                        *(bf16x8*)&sU[r * LD128 + p * 32 + i * 8] = cvt8(src[2 * i], src[2 * i + 1]);
                } else {
                    const uint4* src = (const uint4*)(agg + (size_t)R * 64 + (p - 2) * 32);
                    #pragma unroll
                    for (int i = 0; i < 4; ++i) {
                        uint4 u = src[i];
                        bf16x8 o;
                        o[0] = (bf16)h2f_lo(u.x); o[1] = (bf16)h2f_hi(u.x);
                        o[2] = (bf16)h2f_lo(u.y); o[3] = (bf16)h2f_hi(u.y);
                        o[4] = (bf16)h2f_lo(u.z); o[5] = (bf16)h2f_hi(u.z);
                        o[6] = (bf16)h2f_lo(u.w); o[7] = (bf16)h2f_hi(u.w);
                        *(bf16x8*)&sU[r * LD128 + p * 32 + i * 8] = o;
                    }
                }
            }
        }
        __syncthreads();

        f32x4 acc[4];
        #pragma unroll
        for (int nt = 0; nt < 4; ++nt) acc[nt] = (f32x4){0.f, 0.f, 0.f, 0.f};
        #pragma unroll
        for (int kt = 0; kt < 4; ++kt) {
            bf16x8 a = *(const bf16x8*)&sU[(wave * 16 + l15) * LD128 + kt * 32 + quad * 8];
            #pragma unroll
            for (int nt = 0; nt < 4; ++nt) {
                bf16x8 bfr = *(const bf16x8*)&sW1t[(nt * 16 + l15) * LD128 + kt * 32 + quad * 8];
                acc[nt] = mfma16(a, bfr, acc[nt]);
            }
        }
        #pragma unroll
        for (int nt = 0; nt < 4; ++nt) {
            float bias = sB1[nt * 16 + l15];
            #pragma unroll
            for (int rr = 0; rr < 4; ++rr) {
                float v = acc[nt][rr] + bias;
                v = v > 0.f ? v : 0.f;
                sH[(wave * 16 + quad * 4 + rr) * LD64 + nt * 16 + l15] = (bf16)v;
            }
        }
        __syncthreads();

        f32x4 acc2[4];
        #pragma unroll
        for (int nt = 0; nt < 4; ++nt) acc2[nt] = (f32x4){0.f, 0.f, 0.f, 0.f};
        #pragma unroll
        for (int kt = 0; kt < 2; ++kt) {
            bf16x8 a = *(const bf16x8*)&sH[(wave * 16 + l15) * LD64 + kt * 32 + quad * 8];
            #pragma unroll
            for (int nt = 0; nt < 4; ++nt) {
                bf16x8 bfr = *(const bf16x8*)&sW2t[(nt * 16 + l15) * LD64 + kt * 32 + quad * 8];
                acc2[nt] = mfma16(a, bfr, acc2[nt]);
            }
        }
        #pragma unroll
        for (int nt = 0; nt < 4; ++nt) {
            float bias = sB2[nt * 16 + l15];
            #pragma unroll
            for (int rr = 0; rr < 4; ++rr) {
                int row = wave * 16 + quad * 4 + rr;
                int R = base + row;
                if (R < N)
                    out[(size_t)R * 64 + nt * 16 + l15] = acc2[nt][rr] + bias;
            }
        }
    }
}

// ===========================================================================
extern "C" void kernel_launch(void* const* d_in, const int* in_sizes, int n_in,
                              void* d_out, int out_size, void* d_ws, size_t ws_size,
                              hipStream_t stream) {
    const float* emb    = (const float*)d_in[0];
    const int*   rel1   = (const int*)d_in[1];
    const int*   rel2   = (const int*)d_in[2];
    const float* m1W1   = (const float*)d_in[3];
    const float* m1b1   = (const float*)d_in[4];
    const float* m1W2   = (const float*)d_in[5];
    const float* m1b2   = (const float*)d_in[6];
    const float* m2W1   = (const float*)d_in[7];
    const float* m2b1   = (const float*)d_in[8];
    const float* m2W2   = (const float*)d_in[9];
    const float* m2b2   = (const float*)d_in[10];
    const float* uW1    = (const float*)d_in[11];
    const float* ub1    = (const float*)d_in[12];
    const float* uW2    = (const float*)d_in[13];
    const float* ub2    = (const float*)d_in[14];

    const int N    = in_sizes[0] / 64;   // 100000
    const int M1   = in_sizes[1];        // 500000
    const int M2x2 = in_sizes[2];        // 2000000
    const int M2   = M2x2 / 2;

    // ---- workspace layout (agg lives in d_out) ----
    const int nch   = (N + 511) / 512;
    const int nbins = nch * 512;
    const int nbuckets = (N + 31) / 32;  // 3125
    char* wsb = (char*)d_ws;
    size_t off = 0;
    auto take = [&](size_t bytes) {
        size_t cur = off;
        off = (off + bytes + 255) & ~(size_t)255;
        return cur;
    };
    bf16*     P0   = (bf16*)    (wsb + take((size_t)N * 128 * sizeof(bf16)));
    bf16*     P1   = (bf16*)    (wsb + take((size_t)N * 128 * sizeof(bf16)));
    unsigned* cnt1 = (unsigned*)(wsb + take((size_t)nbins * 4));
    unsigned* cntA = (unsigned*)(wsb + take((size_t)nbins * 4));
    unsigned* cntB = (unsigned*)(wsb + take((size_t)nbins * 4));
    unsigned* rowp = (unsigned*)(wsb + take((size_t)nbins * 4));
    unsigned* csum = (unsigned*)(wsb + take((size_t)(nch + 64) * 4));
    ushort2*  rk2  = (ushort2*) (wsb + take((size_t)M2 * 4));
    int*      sps  = (int*)     (wsb + take((size_t)M2x2 * 4));

    if (off <= ws_size) {
        float* agg = (float*)d_out;      // unscaled rel1 out, then final agg

        // zero cnt1, cntA, cntB (contiguous)
        hipMemsetAsync(cnt1, 0, (size_t)((char*)rowp - (char*)cnt1), stream);

        // 1) histogram with per-slot rank capture
        const int gh = 2048;
        hist_rk_kernel<<<gh, 256, 0, stream>>>(rel1, rel2, cnt1, cntA, cntB,
                                               rk2, M1, M2);

        // 2) scan -> rowp (totals = cntA + cntB)
        scan_sums<<<nch, 256, 0, stream>>>(cntA, cntB, csum);
        scan_chunkoff<<<1, 256, 0, stream>>>(csum, nch);
        scan_apply<<<nch, 256, 0, stream>>>(cntA, cntB, csum, rowp);

        // 3) mix: atomic-free slot-partitioned scatter || prep3 + rel1
        const int SB = 2048;
        const int PT = (N + 63) / 64;    // 1563
        mix_kernel<<<SB + PT, 256, 0, stream>>>(
            rel2, rk2, rowp, cntA, sps, M2, SB,
            emb, m2W1, m2b1, m1W1, m1b1, m1W2, m1b2,
            P0, P1, agg, N, PT);

        // 4) fused aggregation (slot-partitioned single-load walk)
        const int gf = nbuckets < 2048 ? nbuckets : 2048;
        rel2_fused_kernel<<<gf, 256, 0, stream>>>(
            P0, P1, sps, rowp, cntA, cnt1, m2W2, m2b2, agg, N, nbuckets);

        // 5) update
        update_kernel<<<PT, 256, 0, stream>>>(emb, agg, uW1, ub1, uW2, ub2,
                                              (float*)d_out, N, PT);
    } else {
        // ---- fallback: f16 agg + pk atomics (proven) ----
        __half* aggh = (__half*)d_ws;
        hipMemsetAsync(aggh, 0, (size_t)N * 64 * sizeof(__half), stream);

        const int t1 = (M1 + 63) / 64;
        rel1_fb_kernel<<<t1 < 1024 ? t1 : 1024, 256, 0, stream>>>(
            emb, rel1, m1W1, m1b1, m1W2, m1b2, aggh, M1, t1);
        const int t2 = (M2 + 63) / 64;
        rel2_fb_kernel<<<t2 < 2048 ? t2 : 2048, 256, 0, stream>>>(
            emb, rel2, m2W1, m2b1, m2W2, m2b2, aggh, M2, t2);
        const int tu = (N + 63) / 64;
        update_fb_kernel<<<tu, 256, 0, stream>>>(emb, aggh, uW1, ub1, uW2, ub2,
                                                 (float*)d_out, N, tu);
    }
}

// Round 11
// 466.141 us; speedup vs baseline: 1.0077x; 1.0077x over previous
//
#include <hip/hip_runtime.h>
#include <hip/hip_fp16.h>

typedef __bf16 bf16;
typedef bf16 bf16x8 __attribute__((ext_vector_type(8)));
typedef float f32x4 __attribute__((ext_vector_type(4)));

#define LD64  80   // padded LDS row stride (elems) for 64-wide tiles
#define LD128 144  // padded LDS row stride for 128-wide tiles

static __device__ __forceinline__ f32x4 mfma16(bf16x8 a, bf16x8 b, f32x4 c) {
    return __builtin_amdgcn_mfma_f32_16x16x32_bf16(a, b, c, 0, 0, 0);
}

static __device__ __forceinline__ bf16x8 cvt8(float4 a, float4 b) {
    bf16x8 v;
    v[0] = (bf16)a.x; v[1] = (bf16)a.y; v[2] = (bf16)a.z; v[3] = (bf16)a.w;
    v[4] = (bf16)b.x; v[5] = (bf16)b.y; v[6] = (bf16)b.z; v[7] = (bf16)b.w;
    return v;
}

static __device__ __forceinline__ uint32_t pack_bf16(float lo, float hi) {
    bf16 a = (bf16)lo, b = (bf16)hi;
    uint16_t ua = *(uint16_t*)&a, ub = *(uint16_t*)&b;
    return ((uint32_t)ub << 16) | (uint32_t)ua;
}

// --- helpers for the fallback (f16 agg) path ---
static __device__ __forceinline__ uint32_t pack_f16(float lo, float hi) {
    __half hl = __float2half_rn(lo), hh = __float2half_rn(hi);
    uint16_t a = *(uint16_t*)&hl, b = *(uint16_t*)&hh;
    return ((uint32_t)b << 16) | (uint32_t)a;
}
static __device__ __forceinline__ void atomic_pk_f16(__half* addr, uint32_t v) {
    asm volatile("global_atomic_pk_add_f16 %0, %1, off" :: "v"(addr), "v"(v) : "memory");
}
static __device__ __forceinline__ float h2f_lo(uint32_t u) {
    uint16_t s = (uint16_t)u; __half h = *(__half*)&s; return __half2float(h);
}
static __device__ __forceinline__ float h2f_hi(uint32_t u) {
    uint16_t s = (uint16_t)(u >> 16); __half h = *(__half*)&s; return __half2float(h);
}

// ===========================================================================
// hist_rk: histogram of rel1+rel2 dests; rel2 atomics capture the RETURN value
// as the entry's within-node rank -> the later scatter needs no atomics.
// (R9-proven structure: one atomic + one 2B rank write per entry.)
// ===========================================================================
__global__ __launch_bounds__(256) void hist_rk_kernel(
    const int* __restrict__ r1, const int* __restrict__ r2,
    unsigned* __restrict__ cnt1, unsigned* __restrict__ cnt2,
    unsigned short* __restrict__ rk, int M1, int M2x2)
{
    int i = blockIdx.x * 256 + threadIdx.x;
    const int T = gridDim.x * 256;
    const int tot = M1 + M2x2;
    for (; i < tot; i += T) {
        if (i < M1) {
            atomicAdd(&cnt1[r1[i]], 1u);
        } else {
            const int j = i - M1;
            unsigned r = atomicAdd(&cnt2[r2[j]], 1u);
            rk[j] = (unsigned short)r;
        }
    }
}

// ===========================================================================
// Scan chain
// ===========================================================================
__global__ __launch_bounds__(256) void scan_sums(
    const unsigned* __restrict__ cnt, unsigned* __restrict__ csum)
{
    __shared__ unsigned s[256];
    const int b = blockIdx.x, t = threadIdx.x;
    s[t] = cnt[b * 512 + t] + cnt[b * 512 + 256 + t];
    __syncthreads();
    for (int d = 128; d > 0; d >>= 1) {
        if (t < d) s[t] += s[t + d];
        __syncthreads();
    }
    if (t == 0) csum[b] = s[0];
}

__global__ __launch_bounds__(256) void scan_chunkoff(unsigned* __restrict__ csum, int nch) {
    __shared__ unsigned s[2][256];
    const int t = threadIdx.x;
    if (nch > 256) {
        if (t == 0) {
            unsigned run = 0;
            for (int j = 0; j < nch; ++j) { unsigned v = csum[j]; csum[j] = run; run += v; }
        }
        return;
    }
    unsigned v = (t < nch) ? csum[t] : 0u;
    s[0][t] = v;
    __syncthreads();
    int src = 0;
    for (int d = 1; d < 256; d <<= 1) {
        int dst = src ^ 1;
        s[dst][t] = s[src][t] + (t >= d ? s[src][t - d] : 0u);
        __syncthreads();
        src = dst;
    }
    if (t < nch) csum[t] = s[src][t] - v;   // exclusive
}

// rowp[i] <- global exclusive prefix
__global__ __launch_bounds__(256) void scan_apply(
    const unsigned* __restrict__ cnt, const unsigned* __restrict__ csum,
    unsigned* __restrict__ rowp)
{
    __shared__ unsigned s[2][512];
    const int b = blockIdx.x, t = threadIdx.x;
    const unsigned base = csum[b];
    s[0][t] = cnt[b * 512 + t];
    s[0][t + 256] = cnt[b * 512 + t + 256];
    __syncthreads();
    int src = 0;
    for (int d = 1; d < 512; d <<= 1) {
        int dst = src ^ 1;
        for (int i = t; i < 512; i += 256)
            s[dst][i] = s[src][i] + (i >= d ? s[src][i - d] : 0u);
        __syncthreads();
        src = dst;
    }
    for (int i = t; i < 512; i += 256)
        rowp[b * 512 + i] = base + s[src][i] - cnt[b * 512 + i];
}

// ===========================================================================
// MIX: blocks [0,SB) = atomic-free scatter to final dest-sorted positions
//   (pos = rowp[n] + rk[i]); payload = (other<<1)|slot, a single int.
// blocks [SB,...) = prep3 (P0/P1 + unscaled rel1 MLP -> aggu).
// ===========================================================================
__global__ __launch_bounds__(256) void mix_kernel(
    // scatter args
    const int* __restrict__ r2, const unsigned short* __restrict__ rk,
    const unsigned* __restrict__ rowp, int* __restrict__ sps,
    int M2x2, int SB,
    // prep args
    const float* __restrict__ emb,
    const float* __restrict__ mW1, const float* __restrict__ mb1,   // 128x128,128
    const float* __restrict__ r1W1, const float* __restrict__ r1b1, // 64x64,64
    const float* __restrict__ r1W2, const float* __restrict__ r1b2,
    bf16* __restrict__ P0, bf16* __restrict__ P1,
    float* __restrict__ aggu, int N, int PT)
{
    __shared__ bf16 sG[64 * LD64];
    __shared__ bf16 sH[64 * LD64];
    __shared__ bf16 sW1t[64 * LD64];
    __shared__ bf16 sW2t[64 * LD64];
    __shared__ float sB1[64], sB2[64];

    const int t = threadIdx.x;

    if ((int)blockIdx.x < SB) {   // ---- atomic-free scatter ----
        const int T = SB * 256;
        for (int i = blockIdx.x * 256 + t; i < M2x2; i += T) {
            const int2 pr = *(const int2*)(r2 + (i & ~1));
            const int slot = i & 1;
            const int n = slot ? pr.y : pr.x;
            const int other = slot ? pr.x : pr.y;
            const unsigned pos = rowp[n] + (unsigned)rk[i];
            sps[pos] = (other << 1) | slot;
        }
        return;
    }

    // ---- prep3 + rel1 ----
    const int bid = blockIdx.x - SB;
    const int G = gridDim.x - SB;
    const int wave = t >> 6, lane = t & 63;
    const int l15 = lane & 15, quad = lane >> 4;
    const int r = t >> 2, p = t & 3;

    for (int i = t; i < 64 * 64; i += 256) {
        int k = i >> 6, n = i & 63;
        sW1t[n * LD64 + k] = (bf16)r1W1[i];
        sW2t[n * LD64 + k] = (bf16)r1W2[i];
    }
    if (t < 64) { sB1[t] = r1b1[t]; sB2[t] = r1b2[t]; }

    bf16x8 wf0[2][2], wf1[2][2];
    float biasv[2];
    #pragma unroll
    for (int j = 0; j < 2; ++j) {
        const int n = (wave * 2 + j) * 16 + l15;
        biasv[j] = mb1[n];
        #pragma unroll
        for (int kt = 0; kt < 2; ++kt) {
            bf16x8 f0, f1;
            #pragma unroll
            for (int e = 0; e < 8; ++e) {
                int k = kt * 32 + quad * 8 + e;
                f0[e] = (bf16)mW1[k * 128 + n];
                f1[e] = (bf16)mW1[(64 + k) * 128 + n];
            }
            wf0[j][kt] = f0;
            wf1[j][kt] = f1;
        }
    }

    for (int tile = bid; tile < PT; tile += G) {
        __syncthreads();
        const int base = tile * 64;
        const int R = base + r;
        if (R < N) {
            const float4* src = (const float4*)(emb + (size_t)R * 64 + p * 16);
            float4 v0 = src[0], v1 = src[1], v2 = src[2], v3 = src[3];
            *(bf16x8*)&sG[r * LD64 + p * 16 + 0] = cvt8(v0, v1);
            *(bf16x8*)&sG[r * LD64 + p * 16 + 8] = cvt8(v2, v3);
        }
        __syncthreads();

        // --- P-part ---
        f32x4 a0[4][2], a1[4][2];
        #pragma unroll
        for (int mt = 0; mt < 4; ++mt)
            #pragma unroll
            for (int j = 0; j < 2; ++j) {
                a0[mt][j] = (f32x4){0.f, 0.f, 0.f, 0.f};
                a1[mt][j] = (f32x4){0.f, 0.f, 0.f, 0.f};
            }
        #pragma unroll
        for (int mt = 0; mt < 4; ++mt)
            #pragma unroll
            for (int kt = 0; kt < 2; ++kt) {
                bf16x8 a = *(const bf16x8*)&sG[(mt * 16 + l15) * LD64 + kt * 32 + quad * 8];
                #pragma unroll
                for (int j = 0; j < 2; ++j) {
                    a0[mt][j] = mfma16(a, wf0[j][kt], a0[mt][j]);
                    a1[mt][j] = mfma16(a, wf1[j][kt], a1[mt][j]);
                }
            }
        #pragma unroll
        for (int mt = 0; mt < 4; ++mt)
            #pragma unroll
            for (int j = 0; j < 2; ++j) {
                const int colb = (wave * 2 + j) * 16 + (l15 & ~1);
                const int odd = l15 & 1;
                #pragma unroll
                for (int rr = 0; rr < 4; ++rr) {
                    float v = a0[mt][j][rr] + biasv[j];
                    float o = __shfl_xor(v, 1);
                    float w = a1[mt][j][rr];
                    float ow = __shfl_xor(w, 1);
                    if ((rr >> 1) == odd) {
                        int node = base + mt * 16 + quad * 4 + rr;
                        if (node < N) {
                            *(uint32_t*)&P0[(size_t)node * 128 + colb] =
                                odd ? pack_bf16(o, v) : pack_bf16(v, o);
                            *(uint32_t*)&P1[(size_t)node * 128 + colb] =
                                odd ? pack_bf16(ow, w) : pack_bf16(w, ow);
                        }
                    }
                }
            }

        // --- rel1 MLP (unscaled) ---
        f32x4 acc[4];
        #pragma unroll
        for (int nt = 0; nt < 4; ++nt) acc[nt] = (f32x4){0.f, 0.f, 0.f, 0.f};
        #pragma unroll
        for (int kt = 0; kt < 2; ++kt) {
            bf16x8 a = *(const bf16x8*)&sG[(wave * 16 + l15) * LD64 + kt * 32 + quad * 8];
            #pragma unroll
            for (int nt = 0; nt < 4; ++nt) {
                bf16x8 bfr = *(const bf16x8*)&sW1t[(nt * 16 + l15) * LD64 + kt * 32 + quad * 8];
                acc[nt] = mfma16(a, bfr, acc[nt]);
            }
        }
        #pragma unroll
        for (int nt = 0; nt < 4; ++nt) {
            float bias = sB1[nt * 16 + l15];
            #pragma unroll
            for (int rr = 0; rr < 4; ++rr) {
                float v = acc[nt][rr] + bias;
                v = v > 0.f ? v : 0.f;
                sH[(wave * 16 + quad * 4 + rr) * LD64 + nt * 16 + l15] = (bf16)v;
            }
        }
        __syncthreads();

        f32x4 acc2[4];
        #pragma unroll
        for (int nt = 0; nt < 4; ++nt) acc2[nt] = (f32x4){0.f, 0.f, 0.f, 0.f};
        #pragma unroll
        for (int kt = 0; kt < 2; ++kt) {
            bf16x8 a = *(const bf16x8*)&sH[(wave * 16 + l15) * LD64 + kt * 32 + quad * 8];
            #pragma unroll
            for (int nt = 0; nt < 4; ++nt) {
                bf16x8 bfr = *(const bf16x8*)&sW2t[(nt * 16 + l15) * LD64 + kt * 32 + quad * 8];
                acc2[nt] = mfma16(a, bfr, acc2[nt]);
            }
        }
        #pragma unroll
        for (int nt = 0; nt < 4; ++nt) {
            float bias = sB2[nt * 16 + l15];
            #pragma unroll
            for (int rr = 0; rr < 4; ++rr) {
                int row = wave * 16 + quad * 4 + rr;
                int R2 = base + row;
                if (R2 < N)
                    aggu[(size_t)R2 * 64 + nt * 16 + l15] = acc2[nt][rr] + bias;
            }
        }
    }
}

// ===========================================================================
// rel2 fused aggregation: R9's proven combined walk (one long segment per
// node, 8-deep pipeline) + R10's algebra (node's own P-rows cached in
// registers; ONE load per entry with uniform select).
// ===========================================================================
__global__ __launch_bounds__(256) void rel2_fused_kernel(
    const bf16* __restrict__ P0, const bf16* __restrict__ P1,
    const int* __restrict__ sps,
    const unsigned* __restrict__ rowp, const unsigned* __restrict__ cnt1,
    const float* __restrict__ W2, const float* __restrict__ b2,   // 128x128,128
    float* agg, int N, int numGroups)
{
    const int HLD = 136;
    __shared__ bf16 hT[2][32 * 136];
    __shared__ float sCf[2][32];

    const int t = threadIdx.x;
    const int wave = t >> 6, lane = t & 63;
    const int l15 = lane & 15, quad = lane >> 4;

    bf16x8 w2f[2][4];
    #pragma unroll
    for (int s = 0; s < 2; ++s)
        #pragma unroll
        for (int kt = 0; kt < 4; ++kt) {
            bf16x8 f;
            #pragma unroll
            for (int e = 0; e < 8; ++e) {
                int k = kt * 32 + quad * 8 + e;
                f[e] = (bf16)W2[k * 128 + s * 64 + wave * 16 + l15];
            }
            w2f[s][kt] = f;
        }
    const int col = wave * 16 + l15;
    const float b2a = b2[col], b2b = b2[64 + col];

    for (int g = blockIdx.x; g < numGroups; g += gridDim.x) {
        const int gb = g * 32;
        __syncthreads();   // protect hT/sCf against previous group's GEMM

        // ---- walk: wave fills rows [wave*8, wave*8+8) ----
        for (int k = 0; k < 8; ++k) {
            const int n = gb + wave * 8 + k;
            float h0lo = 0.f, h0hi = 0.f, h1lo = 0.f, h1hi = 0.f;
            float c0 = 0.f, c1 = 0.f;
            if (n < N) {
                unsigned e = rowp[n];
                const unsigned end = rowp[n + 1];
                // cache node's own P-rows (constants across the walk)
                const uint32_t pd0 = *(const uint32_t*)(P0 + (size_t)n * 128 + lane * 2);
                const uint32_t pd1 = *(const uint32_t*)(P1 + (size_t)n * 128 + lane * 2);
                const float c0lo = __uint_as_float(pd0 << 16);
                const float c0hi = __uint_as_float(pd0 & 0xffff0000u);
                const float c1lo = __uint_as_float(pd1 << 16);
                const float c1hi = __uint_as_float(pd1 & 0xffff0000u);
                while (e < end) {
                    const int cnt = (int)min(64u, end - e);
                    int pv = 0;
                    if ((int)lane < cnt) pv = sps[e + lane];
                    unsigned long long bm =
                        __ballot(((int)lane < cnt) && (pv & 1));
                    const int n1 = __popcll(bm);
                    c1 += (float)n1;
                    c0 += (float)(cnt - n1);

                    int j = 0;
                    for (; j + 8 <= cnt; j += 8) {     // 8 loads in flight
                        uint32_t dv[8]; int pvv[8];
                        #pragma unroll
                        for (int q = 0; q < 8; ++q) {
                            pvv[q] = __shfl(pv, j + q);
                            const bf16* P = (pvv[q] & 1) ? P0 : P1;
                            dv[q] = *(const uint32_t*)(P + (size_t)(pvv[q] >> 1) * 128 + lane * 2);
                        }
                        #pragma unroll
                        for (int q = 0; q < 8; ++q) {
                            const int slot = pvv[q] & 1;
                            float lo = __uint_as_float(dv[q] << 16) + (slot ? c1lo : c0lo);
                            float hi = __uint_as_float(dv[q] & 0xffff0000u) + (slot ? c1hi : c0hi);
                            lo = fmaxf(lo, 0.f); hi = fmaxf(hi, 0.f);
                            if (slot) { h1lo += lo; h1hi += hi; }
                            else      { h0lo += lo; h0hi += hi; }
                        }
                    }
                    for (; j + 4 <= cnt; j += 4) {
                        uint32_t dv[4]; int pvv[4];
                        #pragma unroll
                        for (int q = 0; q < 4; ++q) {
                            pvv[q] = __shfl(pv, j + q);
                            const bf16* P = (pvv[q] & 1) ? P0 : P1;
                            dv[q] = *(const uint32_t*)(P + (size_t)(pvv[q] >> 1) * 128 + lane * 2);
                        }
                        #pragma unroll
                        for (int q = 0; q < 4; ++q) {
                            const int slot = pvv[q] & 1;
                            float lo = __uint_as_float(dv[q] << 16) + (slot ? c1lo : c0lo);
                            float hi = __uint_as_float(dv[q] & 0xffff0000u) + (slot ? c1hi : c0hi);
                            lo = fmaxf(lo, 0.f); hi = fmaxf(hi, 0.f);
                            if (slot) { h1lo += lo; h1hi += hi; }
                            else      { h0lo += lo; h0hi += hi; }
                        }
                    }
                    for (; j < cnt; ++j) {
                        const int pvq = __shfl(pv, j);
                        const int slot = pvq & 1;
                        const bf16* P = slot ? P0 : P1;
                        const uint32_t d = *(const uint32_t*)(P + (size_t)(pvq >> 1) * 128 + lane * 2);
                        float lo = __uint_as_float(d << 16) + (slot ? c1lo : c0lo);
                        float hi = __uint_as_float(d & 0xffff0000u) + (slot ? c1hi : c0hi);
                        lo = fmaxf(lo, 0.f); hi = fmaxf(hi, 0.f);
                        if (slot) { h1lo += lo; h1hi += hi; }
                        else      { h0lo += lo; h0hi += hi; }
                    }
                    e += cnt;
                }
            }
            const int row = wave * 8 + k;
            *(uint32_t*)&hT[0][row * HLD + lane * 2] = pack_bf16(h0lo, h0hi);
            *(uint32_t*)&hT[1][row * HLD + lane * 2] = pack_bf16(h1lo, h1hi);
            if (lane == 0) { sCf[0][row] = c0; sCf[1][row] = c1; }
        }
        __syncthreads();

        // ---- GEMM: out[32 nodes][wave's 16 cols] = sum_s H_s @ W2half[s] ----
        f32x4 acc[2];
        #pragma unroll
        for (int mt = 0; mt < 2; ++mt) acc[mt] = (f32x4){0.f, 0.f, 0.f, 0.f};
        #pragma unroll
        for (int s = 0; s < 2; ++s)
            #pragma unroll
            for (int mt = 0; mt < 2; ++mt)
                #pragma unroll
                for (int kt = 0; kt < 4; ++kt) {
                    bf16x8 a = *(const bf16x8*)&hT[s][(mt * 16 + l15) * HLD + kt * 32 + quad * 8];
                    acc[mt] = mfma16(a, w2f[s][kt], acc[mt]);
                }
        #pragma unroll
        for (int mt = 0; mt < 2; ++mt)
            #pragma unroll
            for (int rr = 0; rr < 4; ++rr) {
                const int row = mt * 16 + quad * 4 + rr;
                const int n = gb + row;
                if (n < N) {
                    float* ap = agg + (size_t)n * 64 + col;
                    const float au = *ap;                 // unscaled rel1 MLP out
                    *ap = (float)cnt1[n] * au + acc[mt][rr]
                        + sCf[0][row] * b2a + sCf[1][row] * b2b;
                }
            }
    }
}

// ===========================================================================
// update: out = relu([emb||agg] @ W1 + b1) @ W2 + b2 (agg aliases out)
// ===========================================================================
__global__ __launch_bounds__(256) void update_kernel(
    const float* __restrict__ emb, const float* agg,
    const float* __restrict__ W1, const float* __restrict__ b1,  // 128x64, 64
    const float* __restrict__ W2, const float* __restrict__ b2,  // 64x64, 64
    float* out, int N, int numTiles)
{
    __shared__ bf16 sW1t[64 * LD128];
    __shared__ bf16 sW2t[64 * LD64];
    __shared__ bf16 sU[64 * LD128];
    __shared__ bf16 sH[64 * LD64];
    __shared__ float sB1[64], sB2[64];

    const int t = threadIdx.x;
    const int wave = t >> 6, lane = t & 63;
    const int l15 = lane & 15, quad = lane >> 4;
    const int r = t >> 2, p = t & 3;

    for (int i = t; i < 128 * 64; i += 256) {
        int k = i >> 6, n = i & 63;
        sW1t[n * LD128 + k] = (bf16)W1[i];
    }
    for (int i = t; i < 64 * 64; i += 256) {
        int k = i >> 6, n = i & 63;
        sW2t[n * LD64 + k] = (bf16)W2[i];
    }
    if (t < 64) { sB1[t] = b1[t]; sB2[t] = b2[t]; }

    for (int tile = blockIdx.x; tile < numTiles; tile += gridDim.x) {
        __syncthreads();
        const int base = tile * 64;
        {
            const int R = base + r;
            if (R < N) {
                const float* srcp = (p < 2) ? (emb + (size_t)R * 64 + p * 32)
                                            : (agg + (size_t)R * 64 + (p - 2) * 32);
                const float4* src = (const float4*)srcp;
                #pragma unroll
                for (int i = 0; i < 4; ++i)
                    *(bf16x8*)&sU[r * LD128 + p * 32 + i * 8] = cvt8(src[2 * i], src[2 * i + 1]);
            }
        }
        __syncthreads();

        f32x4 acc[4];
        #pragma unroll
        for (int nt = 0; nt < 4; ++nt) acc[nt] = (f32x4){0.f, 0.f, 0.f, 0.f};
        #pragma unroll
        for (int kt = 0; kt < 4; ++kt) {
            bf16x8 a = *(const bf16x8*)&sU[(wave * 16 + l15) * LD128 + kt * 32 + quad * 8];
            #pragma unroll
            for (int nt = 0; nt < 4; ++nt) {
                bf16x8 bfr = *(const bf16x8*)&sW1t[(nt * 16 + l15) * LD128 + kt * 32 + quad * 8];
                acc[nt] = mfma16(a, bfr, acc[nt]);
            }
        }
        #pragma unroll
        for (int nt = 0; nt < 4; ++nt) {
            float bias = sB1[nt * 16 + l15];
            #pragma unroll
            for (int rr = 0; rr < 4; ++rr) {
                float v = acc[nt][rr] + bias;
                v = v > 0.f ? v : 0.f;
                sH[(wave * 16 + quad * 4 + rr) * LD64 + nt * 16 + l15] = (bf16)v;
            }
        }
        __syncthreads();

        f32x4 acc2[4];
        #pragma unroll
        for (int nt = 0; nt < 4; ++nt) acc2[nt] = (f32x4){0.f, 0.f, 0.f, 0.f};
        #pragma unroll
        for (int kt = 0; kt < 2; ++kt) {
            bf16x8 a = *(const bf16x8*)&sH[(wave * 16 + l15) * LD64 + kt * 32 + quad * 8];
            #pragma unroll
            for (int nt = 0; nt < 4; ++nt) {
                bf16x8 bfr = *(const bf16x8*)&sW2t[(nt * 16 + l15) * LD64 + kt * 32 + quad * 8];
                acc2[nt] = mfma16(a, bfr, acc2[nt]);
            }
        }
        #pragma unroll
        for (int nt = 0; nt < 4; ++nt) {
            float bias = sB2[nt * 16 + l15];
            #pragma unroll
            for (int rr = 0; rr < 4; ++rr) {
                int row = wave * 16 + quad * 4 + rr;
                int R = base + row;
                if (R < N)
                    out[(size_t)R * 64 + nt * 16 + l15] = acc2[nt][rr] + bias;
            }
        }
    }
}

// ===========================================================================
// Fallback path (workspace too small): f16 agg + pk atomics (proven).
// ===========================================================================
__global__ __launch_bounds__(256) void rel1_fb_kernel(
    const float* __restrict__ emb, const int* __restrict__ idx,
    const float* __restrict__ W1, const float* __restrict__ b1,
    const float* __restrict__ W2, const float* __restrict__ b2,
    __half* __restrict__ agg, int M, int numTiles)
{
    __shared__ bf16 sW1t[64 * LD64];
    __shared__ bf16 sW2t[64 * LD64];
    __shared__ bf16 sG[64 * LD64];
    __shared__ bf16 sH[64 * LD64];
    __shared__ float sB1[64], sB2[64];
    __shared__ int sIdx[64];

    const int t = threadIdx.x;
    const int wave = t >> 6, lane = t & 63;
    const int l15 = lane & 15, quad = lane >> 4;
    const int r = t >> 2, p = t & 3;

    for (int i = t; i < 64 * 64; i += 256) {
        int k = i >> 6, n = i & 63;
        sW1t[n * LD64 + k] = (bf16)W1[i];
        sW2t[n * LD64 + k] = (bf16)W2[i];
    }
    if (t < 64) { sB1[t] = b1[t]; sB2[t] = b2[t]; }

    for (int tile = blockIdx.x; tile < numTiles; tile += gridDim.x) {
        __syncthreads();
        const int base = tile * 64;
        int id = -1;
        { int R = base + r; if (R < M) id = idx[R]; }
        if (p == 0) sIdx[r] = id;
        if (id >= 0) {
            const float4* src = (const float4*)(emb + (size_t)id * 64 + p * 16);
            float4 v0 = src[0], v1 = src[1], v2 = src[2], v3 = src[3];
            *(bf16x8*)&sG[r * LD64 + p * 16 + 0] = cvt8(v0, v1);
            *(bf16x8*)&sG[r * LD64 + p * 16 + 8] = cvt8(v2, v3);
        }
        __syncthreads();

        f32x4 acc[4];
        #pragma unroll
        for (int nt = 0; nt < 4; ++nt) acc[nt] = (f32x4){0.f, 0.f, 0.f, 0.f};
        #pragma unroll
        for (int kt = 0; kt < 2; ++kt) {
            bf16x8 a = *(const bf16x8*)&sG[(wave * 16 + l15) * LD64 + kt * 32 + quad * 8];
            #pragma unroll
            for (int nt = 0; nt < 4; ++nt) {
                bf16x8 bfr = *(const bf16x8*)&sW1t[(nt * 16 + l15) * LD64 + kt * 32 + quad * 8];
                acc[nt] = mfma16(a, bfr, acc[nt]);
            }
        }
        #pragma unroll
        for (int nt = 0; nt < 4; ++nt) {
            float bias = sB1[nt * 16 + l15];
            #pragma unroll
            for (int rr = 0; rr < 4; ++rr) {
                float v = acc[nt][rr] + bias;
                v = v > 0.f ? v : 0.f;
                sH[(wave * 16 + quad * 4 + rr) * LD64 + nt * 16 + l15] = (bf16)v;
            }
        }
        __syncthreads();

        f32x4 acc2[4];
        #pragma unroll
        for (int nt = 0; nt < 4; ++nt) acc2[nt] = (f32x4){0.f, 0.f, 0.f, 0.f};
        #pragma unroll
        for (int kt = 0; kt < 2; ++kt) {
            bf16x8 a = *(const bf16x8*)&sH[(wave * 16 + l15) * LD64 + kt * 32 + quad * 8];
            #pragma unroll
            for (int nt = 0; nt < 4; ++nt) {
                bf16x8 bfr = *(const bf16x8*)&sW2t[(nt * 16 + l15) * LD64 + kt * 32 + quad * 8];
                acc2[nt] = mfma16(a, bfr, acc2[nt]);
            }
        }
        #pragma unroll
        for (int nt = 0; nt < 4; ++nt) {
            float bias = sB2[nt * 16 + l15];
            const int colb = nt * 16 + (l15 & ~1);
            const int odd = l15 & 1;
            #pragma unroll
            for (int rr = 0; rr < 4; ++rr) {
                float v = acc2[nt][rr] + bias;
                float o = __shfl_xor(v, 1);
                if ((rr >> 1) == odd) {
                    int row = wave * 16 + quad * 4 + rr;
                    int id2 = sIdx[row];
                    if (id2 >= 0)
                        atomic_pk_f16(agg + (size_t)id2 * 64 + colb,
                                      odd ? pack_f16(o, v) : pack_f16(v, o));
                }
            }
        }
    }
}

__global__ __launch_bounds__(256) void rel2_fb_kernel(
    const float* __restrict__ emb, const int* __restrict__ idx,
    const float* __restrict__ W1, const float* __restrict__ b1,
    const float* __restrict__ W2, const float* __restrict__ b2,
    __half* __restrict__ agg, int M, int numTiles)
{
    __shared__ bf16 sG[64 * LD128];
    __shared__ bf16 sH[64 * LD128];
    __shared__ int sIdx[128];

    const int t = threadIdx.x;
    const int wave = t >> 6, lane = t & 63;
    const int l15 = lane & 15, quad = lane >> 4;
    const int r = t >> 2, p = t & 3;

    bf16x8 w1f[2][4], w2f[2][4];
    float bias1[2], bias2[2];
    #pragma unroll
    for (int j = 0; j < 2; ++j) {
        const int n = (wave * 2 + j) * 16 + l15;
        bias1[j] = b1[n];
        bias2[j] = b2[n];
        #pragma unroll
        for (int kt = 0; kt < 4; ++kt) {
            bf16x8 f1, f2;
            #pragma unroll
            for (int e = 0; e < 8; ++e) {
                int k = kt * 32 + quad * 8 + e;
                f1[e] = (bf16)W1[k * 128 + n];
                f2[e] = (bf16)W2[k * 128 + n];
            }
            w1f[j][kt] = f1;
            w2f[j][kt] = f2;
        }
    }

    for (int tile = blockIdx.x; tile < numTiles; tile += gridDim.x) {
        __syncthreads();
        const int base = tile * 64;
        int i0 = -1, i1 = -1;
        { int R = base + r; if (R < M) { i0 = idx[R * 2]; i1 = idx[R * 2 + 1]; } }
        if (p == 0) { sIdx[r * 2] = i0; sIdx[r * 2 + 1] = i1; }
        {
            int myid = (p < 2) ? i0 : i1;
            if (myid >= 0) {
                const float4* src = (const float4*)(emb + (size_t)myid * 64 + (p & 1) * 32);
                #pragma unroll
                for (int i = 0; i < 4; ++i)
                    *(bf16x8*)&sG[r * LD128 + p * 32 + i * 8] = cvt8(src[2 * i], src[2 * i + 1]);
            }
        }
        __syncthreads();

        f32x4 acc[4][2];
        #pragma unroll
        for (int mt = 0; mt < 4; ++mt)
            #pragma unroll
            for (int j = 0; j < 2; ++j) acc[mt][j] = (f32x4){0.f, 0.f, 0.f, 0.f};
        #pragma unroll
        for (int mt = 0; mt < 4; ++mt) {
            #pragma unroll
            for (int kt = 0; kt < 4; ++kt) {
                bf16x8 a = *(const bf16x8*)&sG[(mt * 16 + l15) * LD128 + kt * 32 + quad * 8];
                #pragma unroll
                for (int j = 0; j < 2; ++j) acc[mt][j] = mfma16(a, w1f[j][kt], acc[mt][j]);
            }
        }
        #pragma unroll
        for (int mt = 0; mt < 4; ++mt)
            #pragma unroll
            for (int j = 0; j < 2; ++j) {
                #pragma unroll
                for (int rr = 0; rr < 4; ++rr) {
                    float v = acc[mt][j][rr] + bias1[j];
                    v = v > 0.f ? v : 0.f;
                    sH[(mt * 16 + quad * 4 + rr) * LD128 + (wave * 2 + j) * 16 + l15] = (bf16)v;
                }
            }
        __syncthreads();

        f32x4 acc2[4][2];
        #pragma unroll
        for (int mt = 0; mt < 4; ++mt)
            #pragma unroll
            for (int j = 0; j < 2; ++j) acc2[mt][j] = (f32x4){0.f, 0.f, 0.f, 0.f};
        #pragma unroll
        for (int mt = 0; mt < 4; ++mt) {
            #pragma unroll
            for (int kt = 0; kt < 4; ++kt) {
                bf16x8 a = *(const bf16x8*)&sH[(mt * 16 + l15) * LD128 + kt * 32 + quad * 8];
                #pragma unroll
                for (int j = 0; j < 2; ++j) acc2[mt][j] = mfma16(a, w2f[j][kt], acc2[mt][j]);
            }
        }
        #pragma unroll
        for (int mt = 0; mt < 4; ++mt) {
            #pragma unroll
            for (int j = 0; j < 2; ++j) {
                const int colb = (wave * 2 + j) * 16 + (l15 & ~1);
                const int sel = colb >> 6;
                const int c = colb & 63;
                const int odd = l15 & 1;
                #pragma unroll
                for (int rr = 0; rr < 4; ++rr) {
                    float v = acc2[mt][j][rr] + bias2[j];
                    float o = __shfl_xor(v, 1);
                    if ((rr >> 1) == odd) {
                        int row = mt * 16 + quad * 4 + rr;
                        int id2 = sIdx[row * 2 + sel];
                        if (id2 >= 0)
                            atomic_pk_f16(agg + (size_t)id2 * 64 + c,
                                          odd ? pack_f16(o, v) : pack_f16(v, o));
                    }
                }
            }
        }
    }
}

__global__ __launch_bounds__(256) void update_fb_kernel(
    const float* __restrict__ emb, const __half* __restrict__ agg,
    const float* __restrict__ W1, const float* __restrict__ b1,
    const float* __restrict__ W2, const float* __restrict__ b2,
    float* __restrict__ out, int N, int numTiles)
{
    __shared__ bf16 sW1t[64 * LD128];
    __shared__ bf16 sW2t[64 * LD64];
    __shared__ bf16 sU[64 * LD128];
    __shared__ bf16 sH[64 * LD64];
    __shared__ float sB1[64], sB2[64];

    const int t = threadIdx.x;
    const int wave = t >> 6, lane = t & 63;
    const int l15 = lane & 15, quad = lane >> 4;
    const int r = t >> 2, p = t & 3;

    for (int i = t; i < 128 * 64; i += 256) {
        int k = i >> 6, n = i & 63;
        sW1t[n * LD128 + k] = (bf16)W1[i];
    }
    for (int i = t; i < 64 * 64; i += 256) {
        int k = i >> 6, n = i & 63;
        sW2t[n * LD64 + k] = (bf16)W2[i];
    }
    if (t < 64) { sB1[t] = b1[t]; sB2[t] = b2[t]; }

    for (int tile = blockIdx.x; tile < numTiles; tile += gridDim.x) {
        __syncthreads();
        const int base = tile * 64;
        {
            const int R = base + r;
            if (R < N) {
                if (p < 2) {
                    const float4* src = (const float4*)(emb + (size_t)R * 64 + p * 32);
                    #pragma unroll
                    for (int i = 0; i < 4; ++i)
                        *(bf16x8*)&sU[r * LD128 + p * 32 + i * 8] = cvt8(src[2 * i], src[2 * i + 1]);
                } else {
                    const uint4* src = (const uint4*)(agg + (size_t)R * 64 + (p - 2) * 32);
                    #pragma unroll
                    for (int i = 0; i < 4; ++i) {
                        uint4 u = src[i];
                        bf16x8 o;
                        o[0] = (bf16)h2f_lo(u.x); o[1] = (bf16)h2f_hi(u.x);
                        o[2] = (bf16)h2f_lo(u.y); o[3] = (bf16)h2f_hi(u.y);
                        o[4] = (bf16)h2f_lo(u.z); o[5] = (bf16)h2f_hi(u.z);
                        o[6] = (bf16)h2f_lo(u.w); o[7] = (bf16)h2f_hi(u.w);
                        *(bf16x8*)&sU[r * LD128 + p * 32 + i * 8] = o;
                    }
                }
            }
        }
        __syncthreads();

        f32x4 acc[4];
        #pragma unroll
        for (int nt = 0; nt < 4; ++nt) acc[nt] = (f32x4){0.f, 0.f, 0.f, 0.f};
        #pragma unroll
        for (int kt = 0; kt < 4; ++kt) {
            bf16x8 a = *(const bf16x8*)&sU[(wave * 16 + l15) * LD128 + kt * 32 + quad * 8];
            #pragma unroll
            for (int nt = 0; nt < 4; ++nt) {
                bf16x8 bfr = *(const bf16x8*)&sW1t[(nt * 16 + l15) * LD128 + kt * 32 + quad * 8];
                acc[nt] = mfma16(a, bfr, acc[nt]);
            }
        }
        #pragma unroll
        for (int nt = 0; nt < 4; ++nt) {
            float bias = sB1[nt * 16 + l15];
            #pragma unroll
            for (int rr = 0; rr < 4; ++rr) {
                float v = acc[nt][rr] + bias;
                v = v > 0.f ? v : 0.f;
                sH[(wave * 16 + quad * 4 + rr) * LD64 + nt * 16 + l15] = (bf16)v;
            }
        }
        __syncthreads();

        f32x4 acc2[4];
        #pragma unroll
        for (int nt = 0; nt < 4; ++nt) acc2[nt] = (f32x4){0.f, 0.f, 0.f, 0.f};
        #pragma unroll
        for (int kt = 0; kt < 2; ++kt) {
            bf16x8 a = *(const bf16x8*)&sH[(wave * 16 + l15) * LD64 + kt * 32 + quad * 8];
            #pragma unroll
            for (int nt = 0; nt < 4; ++nt) {
                bf16x8 bfr = *(const bf16x8*)&sW2t[(nt * 16 + l15) * LD64 + kt * 32 + quad * 8];
                acc2[nt] = mfma16(a, bfr, acc2[nt]);
            }
        }
        #pragma unroll
        for (int nt = 0; nt < 4; ++nt) {
            float bias = sB2[nt * 16 + l15];
            #pragma unroll
            for (int rr = 0; rr < 4; ++rr) {
                int row = wave * 16 + quad * 4 + rr;
                int R = base + row;
                if (R < N)
                    out[(size_t)R * 64 + nt * 16 + l15] = acc2[nt][rr] + bias;
            }
        }
    }
}

// ===========================================================================
extern "C" void kernel_launch(void* const* d_in, const int* in_sizes, int n_in,
                              void* d_out, int out_size, void* d_ws, size_t ws_size,
                              hipStream_t stream) {
    const float* emb    = (const float*)d_in[0];
    const int*   rel1   = (const int*)d_in[1];
    const int*   rel2   = (const int*)d_in[2];
    const float* m1W1   = (const float*)d_in[3];
    const float* m1b1   = (const float*)d_in[4];
    const float* m1W2   = (const float*)d_in[5];
    const float* m1b2   = (const float*)d_in[6];
    const float* m2W1   = (const float*)d_in[7];
    const float* m2b1   = (const float*)d_in[8];
    const float* m2W2   = (const float*)d_in[9];
    const float* m2b2   = (const float*)d_in[10];
    const float* uW1    = (const float*)d_in[11];
    const float* ub1    = (const float*)d_in[12];
    const float* uW2    = (const float*)d_in[13];
    const float* ub2    = (const float*)d_in[14];

    const int N    = in_sizes[0] / 64;   // 100000
    const int M1   = in_sizes[1];        // 500000
    const int M2x2 = in_sizes[2];        // 2000000
    const int M2   = M2x2 / 2;

    // ---- workspace layout (agg lives in d_out) ----
    const int nch   = (N + 511) / 512;
    const int nbins = nch * 512;
    const int nbuckets = (N + 31) / 32;  // 3125
    char* wsb = (char*)d_ws;
    size_t off = 0;
    auto take = [&](size_t bytes) {
        size_t cur = off;
        off = (off + bytes + 255) & ~(size_t)255;
        return cur;
    };
    bf16*           P0   = (bf16*)          (wsb + take((size_t)N * 128 * sizeof(bf16)));
    bf16*           P1   = (bf16*)          (wsb + take((size_t)N * 128 * sizeof(bf16)));
    unsigned*       cnt1 = (unsigned*)      (wsb + take((size_t)nbins * 4));
    unsigned*       cnt2 = (unsigned*)      (wsb + take((size_t)nbins * 4));
    unsigned*       rowp = (unsigned*)      (wsb + take((size_t)nbins * 4));
    unsigned*       csum = (unsigned*)      (wsb + take((size_t)(nch + 64) * 4));
    unsigned short* rk   = (unsigned short*)(wsb + take((size_t)M2x2 * 2));
    int*            sps  = (int*)           (wsb + take((size_t)M2x2 * 4));

    if (off <= ws_size) {
        float* agg = (float*)d_out;      // unscaled rel1 out, then final agg

        hipMemsetAsync(cnt1, 0, (size_t)((char*)rowp - (char*)cnt1), stream);

        // 1) histogram with rank capture (rel2 atomics return within-node rank)
        const int gh = 2048;
        hist_rk_kernel<<<gh, 256, 0, stream>>>(rel1, rel2, cnt1, cnt2, rk, M1, M2x2);

        // 2) scan -> rowp
        scan_sums<<<nch, 256, 0, stream>>>(cnt2, csum);
        scan_chunkoff<<<1, 256, 0, stream>>>(csum, nch);
        scan_apply<<<nch, 256, 0, stream>>>(cnt2, csum, rowp);

        // 3) mix: atomic-free scatter (packed int payload) || prep3 + rel1
        const int SB = 2048;
        const int PT = (N + 63) / 64;    // 1563
        mix_kernel<<<SB + PT, 256, 0, stream>>>(
            rel2, rk, rowp, sps, M2x2, SB,
            emb, m2W1, m2b1, m1W1, m1b1, m1W2, m1b2,
            P0, P1, agg, N, PT);

        // 4) fused aggregation (combined walk + cached own-row, 1 load/entry)
        const int gf = nbuckets < 2048 ? nbuckets : 2048;
        rel2_fused_kernel<<<gf, 256, 0, stream>>>(
            P0, P1, sps, rowp, cnt1, m2W2, m2b2, agg, N, nbuckets);

        // 5) update
        update_kernel<<<PT, 256, 0, stream>>>(emb, agg, uW1, ub1, uW2, ub2,
                                              (float*)d_out, N, PT);
    } else {
        // ---- fallback: f16 agg + pk atomics (proven) ----
        __half* aggh = (__half*)d_ws;
        hipMemsetAsync(aggh, 0, (size_t)N * 64 * sizeof(__half), stream);

        const int t1 = (M1 + 63) / 64;
        rel1_fb_kernel<<<t1 < 1024 ? t1 : 1024, 256, 0, stream>>>(
            emb, rel1, m1W1, m1b1, m1W2, m1b2, aggh, M1, t1);
        const int t2 = (M2 + 63) / 64;
        rel2_fb_kernel<<<t2 < 2048 ? t2 : 2048, 256, 0, stream>>>(
            emb, rel2, m2W1, m2b1, m2W2, m2b2, aggh, M2, t2);
        const int tu = (N + 63) / 64;
        update_fb_kernel<<<tu, 256, 0, stream>>>(emb, aggh, uW1, ub1, uW2, ub2,
                                                 (float*)d_out, N, tu);
    }
}